// Round 1
// baseline (111.780 us; speedup 1.0000x reference)
//
#include <hip/hip_runtime.h>
#include <stdint.h>

// SpottingLoss: B=2048 batches, N=64 slots, F=19 features.
// Two-phase greedy bipartite matching (lax.scan, length 64 each) then
// permuted YOLO-ish loss summed over ALL axes -> single float output.
//
// Exactness argument (carried over + extended):
//  - alpha in {0,1}; v,h stay {0,1}; D2 = D1 * (0/1 masks), so masking D1
//    (fp32, 1-|x-p|, bit-identical) by the live-column bitmask reproduces D2.
//  - x,p ~ U[0,1): |x-p| <= 1-2^-24 < 1, so D1 > 0 strictly. Every live row
//    always has a positive unkilled candidate (columns alive >= live rows).
//  - Row argmax ties -> first index. A live row's successive proposals are
//    exactly its columns in descending D1 order (skipping killed), because
//    every proposed column is matched+killed the same round. So a per-row
//    preference list sorted by key = ((0x40000000 - bits(D1))<<6 | j)
//    ascending (D1 desc, j asc on ties; D1 in (0,1] -> bits in
//    [1,0x3F800000] -> flipped value fits 30 bits, key exact in 36 bits)
//    popped past killed columns reproduces the rescan argmax bitwise.
//    val at propose time is recomputed as 1-|x-p_sh[c]| -- the identical
//    fp32 expression used to build the keys -> bit-identical.
//  - Column argmax: packed key (val_bits<<6 | 63-row): monotone in val
//    (val>0), larger 63-row == smaller row == first index. No-proposer
//    columns keep key<=63 -> no kill -> no match (matches reference, where
//    an all-zero column's argmax row 0 never forms a mutual pair).
//  - key_sh needs no per-round reset: any proposed column is killed that
//    round and never popped again; stale kills in the ballot only re-clear
//    already-cleared hbits bits.
//  - Early exit when ballot(v)==0: remaining reference scan steps are no-ops
//    (E==0, v/h unchanged). Unmatched rows keep perm=0 == argmax of zero row.

#define NN 64
#define NF 19
typedef unsigned long long u64;

__global__ __launch_bounds__(64, 2) void spotting_loss_kernel(
    const float* __restrict__ yt, const float* __restrict__ yp,
    float* __restrict__ out)
{
  const int b = blockIdx.x;
  const int i = threadIdx.x;  // row index == lane (one wave per block)
  const float* __restrict__ ytb = yt + (size_t)b * NN * NF;
  const float* __restrict__ ypb = yp + (size_t)b * NN * NF;

  __shared__ float p_sh[NN];
  __shared__ u64 key_sh[NN];
  // Sorted preference lists: 64 col-bytes per row packed 4/word.
  // Row stride 17 words (68 B): 17 odd -> i*17 mod 32 covers all banks
  // (2 lanes/bank on uniform reads == free).
  __shared__ unsigned int pref[NN][17];

  const float alpha = ytb[i * NF + 0];
  const float x     = ytb[i * NF + 1];
  p_sh[i]   = ypb[i * NF + 1];
  key_sh[i] = 63ull;  // (val=0,row=0) baseline; never reset again
  __syncthreads();

  // ---- build per-row sort keys (full D1 row) ----
  u64 k[NN];
#pragma unroll
  for (int j = 0; j < NN; ++j) {
    const float d = 1.0f - fabsf(x - p_sh[j]);
    k[j] = (((u64)(0x40000000u - __float_as_uint(d))) << 6) | (u64)j;
  }

  // ---- bitonic sort ascending: D1 desc, col asc on exact ties ----
#pragma unroll
  for (int sz = 2; sz <= NN; sz <<= 1) {
#pragma unroll
    for (int st = sz >> 1; st > 0; st >>= 1) {
#pragma unroll
      for (int t = 0; t < NN; ++t) {
        const int u = t ^ st;
        if (u > t) {
          const bool up = ((t & sz) == 0);
          const u64 a = k[t], c2 = k[u];
          const bool sw = up ? (a > c2) : (a < c2);
          k[t] = sw ? c2 : a;
          k[u] = sw ? a : c2;
        }
      }
    }
  }

  // ---- pack sorted col indices into own LDS row (self-read only) ----
#pragma unroll
  for (int r = 0; r < NN; r += 4) {
    pref[i][r >> 2] = (unsigned)(k[r] & 63ull)
                    | ((unsigned)(k[r + 1] & 63ull) << 8)
                    | ((unsigned)(k[r + 2] & 63ull) << 16)
                    | ((unsigned)(k[r + 3] & 63ull) << 24);
  }
  // no barrier needed: each lane reads only its own pref row; p_sh/key_sh
  // visibility was established by the barrier above.

  const unsigned int* __restrict__ prow = &pref[i][0];
  u64 hbits = ~0ull;   // column j alive <=> bit j set (wave-uniform)
  int perm  = 0;       // matched column (argmax of zero row -> 0)
  int ptr   = 0;       // rank pointer into sorted preference list
  int wptr  = -1;      // word index currently cached in win
  unsigned win = 0;

#pragma unroll 1
  for (int phase = 0; phase < 2; ++phase) {
    // phase 0: v0 = alpha ; phase 1: v0 = 1-alpha
    bool vlive = (phase == 0) ? (alpha > 0.5f) : (alpha < 0.5f);

#pragma unroll 1
    for (int it = 0; it < NN; ++it) {
      if (__ballot(vlive) == 0ull) break;  // remaining steps are no-ops

      int  c = 0;
      bool found = false;
      if (vlive) {
        // pop first unkilled column from sorted preference list
        while (ptr < NN) {
          const int wi = ptr >> 2;
          if (wi != wptr) { win = prow[wi]; wptr = wi; }
          const int cc = (win >> ((ptr & 3) * 8)) & 63;
          if ((hbits >> cc) & 1ull) { c = cc; found = true; break; }
          ++ptr;
        }
        if (found) {
          const float val = 1.0f - fabsf(x - p_sh[c]);  // == D1[i][c] bitwise
          const u64 key = (((u64)__float_as_uint(val)) << 6) |
                          (u64)(63 - i);
          atomicMax(&key_sh[c], key);
        }
      }
      __syncthreads();

      // column side (lane i == column i): cumulative kill ballot (stale ok)
      const u64 kc = key_sh[i];
      const bool colkill = (kc >> 6) != 0ull;
      const u64 killed = __ballot(colkill);

      if (found) {
        const u64 kw = key_sh[c];
        if ((int)(kw & 63ull) == 63 - i) {  // mutual match: Permut[i][c]=1
          perm  = c;
          vlive = false;
        }
        // else: c was proposed (by us) hence killed; next pop advances.
      }
      hbits &= ~killed;
      __syncthreads();  // order this round's reads vs next round's atomics
    }
  }

  // ----- loss -----
  const float* __restrict__ ypr = ypb + (size_t)perm * NF;
  const float a  = alpha;
  const float p0 = ypr[0];
  const float p1 = ypr[1];
  const float dx = x - p1;
  const float da = a - p0;
  float s2 = 0.0f;
#pragma unroll
  for (int f = 2; f < NF; ++f) {
    const float d = ytb[i * NF + f] - ypr[f];
    s2 += d * d;
  }
  float l = a * 5.0f * (dx * dx)
          + a * (da * da)
          + (1.0f - a) * 0.5f * (da * da)
          + a * s2;

  // wave-64 reduction, one atomic per block
#pragma unroll
  for (int off = 32; off > 0; off >>= 1) l += __shfl_down(l, off);
  if (i == 0) atomicAdd(out, l);
}

extern "C" void kernel_launch(void* const* d_in, const int* in_sizes, int n_in,
                              void* d_out, int out_size, void* d_ws, size_t ws_size,
                              hipStream_t stream) {
  const float* yt = (const float*)d_in[0];
  const float* yp = (const float*)d_in[1];
  float* out = (float*)d_out;
  const int B = in_sizes[0] / (NN * NF);

  // harness poisons d_out with 0xAA before every timed replay
  hipMemsetAsync(out, 0, sizeof(float) * (size_t)out_size, stream);
  spotting_loss_kernel<<<B, 64, 0, stream>>>(yt, yp, out);
}

// Round 2
// 108.249 us; speedup vs baseline: 1.0326x; 1.0326x over previous
//
#include <hip/hip_runtime.h>
#include <stdint.h>

// SpottingLoss: B=2048 batches, N=64 slots, F=19 features.
// Two-phase greedy bipartite matching (lax.scan, length 64 each) then
// permuted YOLO-ish loss summed over ALL axes -> single float output.
//
// Exactness argument (verified absmax 0.0 in round-0 form):
//  - alpha in {0.0,1.0}; v,h stay exactly {0.0,1.0}; D2 = D1 * (0/1 factors),
//    so masking D1 (fp32, 1 - |x-p|, bit-identical to numpy) by the current
//    column-active bitmask reproduces D2 values bitwise.
//  - jnp.argmax ties -> first index. Row scan uses strict '>' over masked
//    values. Column argmax uses packed key (val_bits<<6 | (63-row)):
//    monotone in val (val>0), larger 63-row == smaller row == first index.
//    All-zero column -> winner row 0, reproduced by key init (val=0,row=0)=63.
//  - Dead rows (v=0) only ever contribute zeros downstream; their jmax is
//    irrelevant (proved: mval = v*best = 0, matched requires v=1).
//  - Early exit when ballot(v)==0: all remaining scan steps are no-ops (E==0).
//
// Round-2 change (single mechanism vs 54.2us baseline): the final
// grid-wide sum no longer uses 2048 same-address global atomicAdds (theory:
// ~60cy serialized L2 RMW each ~= 120k cycles ~= the entire 54us wall).
// Each block plain-stores its partial to ws[b] (distinct addresses, no
// contention); a 1-block reduce kernel sums ws[0..B) -> out[0]. Kernel
// boundary provides device-wide visibility of the stores.

#define NN 64
#define NF 19

__global__ __launch_bounds__(64) void spotting_loss_kernel(
    const float* __restrict__ yt, const float* __restrict__ yp,
    float* __restrict__ ws)
{
  const int b = blockIdx.x;
  const int i = threadIdx.x;  // row index == lane (one wave per block)
  const float* __restrict__ ytb = yt + (size_t)b * NN * NF;
  const float* __restrict__ ypb = yp + (size_t)b * NN * NF;

  __shared__ float p_sh[NN];
  __shared__ unsigned long long key_sh[NN];

  const float alpha = ytb[i * NF + 0];
  const float x     = ytb[i * NF + 1];
  p_sh[i] = ypb[i * NF + 1];
  __syncthreads();

  // D1 row in registers (fully unrolled, constant indices only).
  float D1r[NN];
#pragma unroll
  for (int j = 0; j < NN; ++j) {
    D1r[j] = 1.0f - fabsf(x - p_sh[j]);
  }

  unsigned long long hbits = ~0ull;  // column j active <=> bit j set
  int   perm  = 0;                   // matched column (argmax of zero row -> 0)
  int   jmax  = 0;
  float best  = 0.0f;

  for (int phase = 0; phase < 2; ++phase) {
    // phase 0: v0 = alpha ; phase 1: v0 = 1-alpha (neg rows untouched by ph.0)
    bool vlive  = (phase == 0) ? (alpha > 0.5f) : (alpha < 0.5f);
    bool rescan = vlive;

    for (int it = 0; it < NN; ++it) {
      if (__ballot(vlive) == 0ull) break;  // remaining steps are no-ops

      if (rescan) {
        // first-index argmax over D1 masked by active columns
        const unsigned hlo = (unsigned)hbits;
        const unsigned hhi = (unsigned)(hbits >> 32);
        best = -1.0f; jmax = 0;
#pragma unroll
        for (int j = 0; j < NN; ++j) {
          const unsigned bit = (j < 32) ? ((hlo >> j) & 1u)
                                        : ((hhi >> (j - 32)) & 1u);
          const unsigned msk = 0u - bit;  // 0xFFFFFFFF or 0
          const float t = __uint_as_float(__float_as_uint(D1r[j]) & msk);
          if (t > best) { best = t; jmax = j; }
        }
        rescan = false;
      }

      key_sh[i] = 63ull;  // (val=0, row=0) baseline: zero column -> winner 0
      __syncthreads();

      if (vlive && best > 0.0f) {
        const unsigned long long key =
            (((unsigned long long)__float_as_uint(best)) << 6) |
            (unsigned long long)(63 - i);
        atomicMax(&key_sh[jmax], key);
      }
      __syncthreads();

      // column side (lane i == column i): any positive write <=> one match
      const unsigned long long kc = key_sh[i];
      const bool colkill = (kc >> 6) != 0ull;
      const unsigned long long killed = __ballot(colkill);

      if (vlive) {
        const unsigned long long kw = key_sh[jmax];
        const int winner = 63 - (int)(kw & 63ull);
        if (winner == i) {            // mutual match: Permut[i][jmax] = 1
          perm = jmax;
          vlive = false;
        } else if ((killed >> jmax) & 1ull) {
          rescan = true;              // favorite column taken by another row
        }
      }
      hbits &= ~killed;
      __syncthreads();
    }
  }

  // ----- loss -----
  const float* __restrict__ ypr = ypb + (size_t)perm * NF;
  const float a  = alpha;
  const float p0 = ypr[0];
  const float p1 = ypr[1];
  const float dx = x - p1;
  const float da = a - p0;
  float s2 = 0.0f;
#pragma unroll
  for (int f = 2; f < NF; ++f) {
    const float d = ytb[i * NF + f] - ypr[f];
    s2 += d * d;
  }
  float l = a * 5.0f * (dx * dx)
          + a * (da * da)
          + (1.0f - a) * 0.5f * (da * da)
          + a * s2;

  // wave-64 reduction, one plain store per block (no atomic contention)
#pragma unroll
  for (int off = 32; off > 0; off >>= 1) l += __shfl_down(l, off);
  if (i == 0) ws[b] = l;
}

__global__ __launch_bounds__(256) void reduce_ws_kernel(
    const float* __restrict__ ws, float* __restrict__ out, int nb)
{
  const int t = threadIdx.x;
  float s = 0.0f;
  for (int j = t; j < nb; j += 256) s += ws[j];
  __shared__ float part[4];
#pragma unroll
  for (int off = 32; off > 0; off >>= 1) s += __shfl_down(s, off);
  if ((t & 63) == 0) part[t >> 6] = s;
  __syncthreads();
  if (t == 0) out[0] = part[0] + part[1] + part[2] + part[3];
}

extern "C" void kernel_launch(void* const* d_in, const int* in_sizes, int n_in,
                              void* d_out, int out_size, void* d_ws, size_t ws_size,
                              hipStream_t stream) {
  const float* yt = (const float*)d_in[0];
  const float* yp = (const float*)d_in[1];
  float* out = (float*)d_out;
  float* ws  = (float*)d_ws;
  const int B = in_sizes[0] / (NN * NF);

  // harness poisons d_out with 0xAA; out[0] is fully overwritten by the
  // reduce kernel. Zero any additional output slots (none expected).
  if (out_size > 1) {
    hipMemsetAsync(out, 0, sizeof(float) * (size_t)out_size, stream);
  }
  spotting_loss_kernel<<<B, 64, 0, stream>>>(yt, yp, ws);
  reduce_ws_kernel<<<1, 256, 0, stream>>>(ws, out, B);
}